// Round 24
// baseline (110.707 us; speedup 1.0000x reference)
//
#include <hip/hip_runtime.h>
#include <hip/hip_bf16.h>
#include <cstddef>

typedef __attribute__((ext_vector_type(8))) short short8;
typedef __attribute__((ext_vector_type(4))) float f32x4;

__device__ inline unsigned short f2bf(float f) {
  unsigned int u = __float_as_uint(f);
  u += 0x7fffu + ((u >> 16) & 1u);
  return (unsigned short)(u >> 16);
}
__device__ inline unsigned int pkbf(float a, float b) {
  __hip_bfloat162 h = __float22bfloat162_rn(make_float2(a, b));
  union { __hip_bfloat162 h2; unsigned int u; } cv;
  cv.h2 = h;
  return cv.u;
}
__device__ inline float bf2f_lo(unsigned int u) {
  return __uint_as_float(u << 16);
}
__device__ inline float bf2f_hi(unsigned int u) {
  return __uint_as_float(u & 0xFFFF0000u);
}

// Fused prep: z=0/1/2 -> transpose+cast Wq/Wkv/Wo; z=3 -> mask AND-patterns.
__global__ __launch_bounds__(256) void prep_kernel(
    const float* __restrict__ Wq, const float* __restrict__ Wkv,
    const float* __restrict__ Wo, const int* __restrict__ mask,
    unsigned short* __restrict__ Wq_t, unsigned short* __restrict__ Wkv_t,
    unsigned short* __restrict__ Wo_t, unsigned int* __restrict__ pmask) {
  const int z = blockIdx.z;
  if (z == 3) {
    if (blockIdx.y != 0) return;
    int idx = blockIdx.x * 256 + threadIdx.x;  // 0..4095
    int bb = idx >> 10, rem = idx & 1023;
    int g = rem >> 5, rem2 = rem & 31;
    int lqv = rem2 >> 3, e = rem2 & 7;
    int ct = e >> 1, half = e & 1;
    // key kappa(ct,lq,j) = (j>>1)*32 + lq*8 + 2ct + (j&1); u32 packs j=2h,2h+1
    int key0 = g * 64 + half * 32 + lqv * 8 + 2 * ct;
    const int* mb = mask + bb * 2048;
    pmask[idx] = (mb[key0] ? 0xFFFFu : 0u) | (mb[key0 + 1] ? 0xFFFF0000u : 0u);
    return;
  }
  const float* src = (z == 0) ? Wq : (z == 1) ? Wkv : Wo;
  unsigned short* dst = (z == 0) ? Wq_t : (z == 1) ? Wkv_t : Wo_t;
  const int R = 512, C = (z == 1) ? 1024 : 512;
  if (blockIdx.x * 64 >= C) return;  // block-uniform
  __shared__ float tile[64][65];
  int c0 = blockIdx.x * 64, r0 = blockIdx.y * 64;
  int tx = threadIdx.x & 63, ty = threadIdx.x >> 6;
  for (int i = ty; i < 64; i += 4)
    tile[i][tx] = src[(size_t)(r0 + i) * C + c0 + tx];
  __syncthreads();
  for (int i = ty; i < 64; i += 4)
    dst[(size_t)(c0 + i) * R + r0 + tx] = f2bf(tile[tx][i]);
}

// Fused q+kv projection, r23 reg-prefetch pipeline (measured ~24us).
__global__ __launch_bounds__(256, 3) void proj_kernel(
    const float* __restrict__ x, const float* __restrict__ context,
    const unsigned short* __restrict__ Wq_t, const unsigned short* __restrict__ Wkv_t,
    unsigned short* __restrict__ qb, unsigned short* __restrict__ kb,
    unsigned short* __restrict__ vtb, float qscale) {
  __shared__ unsigned short As[128][72];
  __shared__ unsigned short Bs[128][72];
  const int bid = blockIdx.x;
  const bool isq = bid < 256;  // block-uniform
  const int lid = isq ? bid : bid - 256;
  const float* Af = isq ? x : context;
  const unsigned short* Bt = isq ? Wq_t : Wkv_t;
  const int bn = (isq ? (lid & 3) : (lid & 7)) * 128;
  const int bm = (isq ? (lid >> 2) : (lid >> 3)) * 128;
  const int K = 512;
  const int tid = threadIdx.x;
  const int wave = tid >> 6, lane = tid & 63;
  const int wr = (wave >> 1) * 64, wc = (wave & 1) * 64;
  const int l15 = lane & 15, lq = lane >> 4;
  const int sr = tid >> 3, sc = (tid & 7) * 8;
  f32x4 acc[4][4] = {};

  // prefetch K-chunk 0 (named scalars only)
  float4 fA0a = *(const float4*)(Af + (size_t)(bm + sr) * K + sc);
  float4 fA0b = *(const float4*)(Af + (size_t)(bm + sr) * K + sc + 4);
  float4 fA1a = *(const float4*)(Af + (size_t)(bm + sr + 32) * K + sc);
  float4 fA1b = *(const float4*)(Af + (size_t)(bm + sr + 32) * K + sc + 4);
  float4 fA2a = *(const float4*)(Af + (size_t)(bm + sr + 64) * K + sc);
  float4 fA2b = *(const float4*)(Af + (size_t)(bm + sr + 64) * K + sc + 4);
  float4 fA3a = *(const float4*)(Af + (size_t)(bm + sr + 96) * K + sc);
  float4 fA3b = *(const float4*)(Af + (size_t)(bm + sr + 96) * K + sc + 4);
  uint4 uB0 = *(const uint4*)(Bt + (size_t)(bn + sr) * K + sc);
  uint4 uB1 = *(const uint4*)(Bt + (size_t)(bn + sr + 32) * K + sc);
  uint4 uB2 = *(const uint4*)(Bt + (size_t)(bn + sr + 64) * K + sc);
  uint4 uB3 = *(const uint4*)(Bt + (size_t)(bn + sr + 96) * K + sc);

  for (int k0 = 0; k0 < K; k0 += 64) {
    __syncthreads();  // BAR-A (WAR)
    uint4 u;
    u.x = pkbf(fA0a.x, fA0a.y); u.y = pkbf(fA0a.z, fA0a.w);
    u.z = pkbf(fA0b.x, fA0b.y); u.w = pkbf(fA0b.z, fA0b.w);
    *(uint4*)(&As[sr][sc]) = u;
    u.x = pkbf(fA1a.x, fA1a.y); u.y = pkbf(fA1a.z, fA1a.w);
    u.z = pkbf(fA1b.x, fA1b.y); u.w = pkbf(fA1b.z, fA1b.w);
    *(uint4*)(&As[sr + 32][sc]) = u;
    u.x = pkbf(fA2a.x, fA2a.y); u.y = pkbf(fA2a.z, fA2a.w);
    u.z = pkbf(fA2b.x, fA2b.y); u.w = pkbf(fA2b.z, fA2b.w);
    *(uint4*)(&As[sr + 64][sc]) = u;
    u.x = pkbf(fA3a.x, fA3a.y); u.y = pkbf(fA3a.z, fA3a.w);
    u.z = pkbf(fA3b.x, fA3b.y); u.w = pkbf(fA3b.z, fA3b.w);
    *(uint4*)(&As[sr + 96][sc]) = u;
    *(uint4*)(&Bs[sr][sc])      = uB0;
    *(uint4*)(&Bs[sr + 32][sc]) = uB1;
    *(uint4*)(&Bs[sr + 64][sc]) = uB2;
    *(uint4*)(&Bs[sr + 96][sc]) = uB3;
    __syncthreads();  // BAR-B (RAW); prefetch never crosses a barrier
    if (k0 + 64 < K) {
      const int kn = k0 + 64;
      fA0a = *(const float4*)(Af + (size_t)(bm + sr) * K + kn + sc);
      fA0b = *(const float4*)(Af + (size_t)(bm + sr) * K + kn + sc + 4);
      fA1a = *(const float4*)(Af + (size_t)(bm + sr + 32) * K + kn + sc);
      fA1b = *(const float4*)(Af + (size_t)(bm + sr + 32) * K + kn + sc + 4);
      fA2a = *(const float4*)(Af + (size_t)(bm + sr + 64) * K + kn + sc);
      fA2b = *(const float4*)(Af + (size_t)(bm + sr + 64) * K + kn + sc + 4);
      fA3a = *(const float4*)(Af + (size_t)(bm + sr + 96) * K + kn + sc);
      fA3b = *(const float4*)(Af + (size_t)(bm + sr + 96) * K + kn + sc + 4);
      uB0 = *(const uint4*)(Bt + (size_t)(bn + sr) * K + kn + sc);
      uB1 = *(const uint4*)(Bt + (size_t)(bn + sr + 32) * K + kn + sc);
      uB2 = *(const uint4*)(Bt + (size_t)(bn + sr + 64) * K + kn + sc);
      uB3 = *(const uint4*)(Bt + (size_t)(bn + sr + 96) * K + kn + sc);
    }
#pragma unroll
    for (int kk = 0; kk < 2; ++kk) {
      short8 af[4], bfr[4];
#pragma unroll
      for (int mt = 0; mt < 4; ++mt)
        af[mt] = *(const short8*)(&As[wr + mt * 16 + l15][kk * 32 + lq * 8]);
#pragma unroll
      for (int nt = 0; nt < 4; ++nt)
        bfr[nt] = *(const short8*)(&Bs[wc + nt * 16 + l15][kk * 32 + lq * 8]);
#pragma unroll
      for (int mt = 0; mt < 4; ++mt)
#pragma unroll
        for (int nt = 0; nt < 4; ++nt)
          acc[mt][nt] = __builtin_amdgcn_mfma_f32_16x16x32_bf16(af[mt], bfr[nt], acc[mt][nt], 0, 0, 0);
    }
  }

#pragma unroll
  for (int mt = 0; mt < 4; ++mt)
#pragma unroll
    for (int nt = 0; nt < 4; ++nt) {
      int row0 = bm + wr + mt * 16 + lq * 4;
      int col = bn + wc + nt * 16 + l15;
      if (isq) {
#pragma unroll
        for (int j = 0; j < 4; ++j)
          qb[(size_t)(row0 + j) * 512 + col] = f2bf(acc[mt][nt][j] * qscale);
      } else if (col < 512) {
#pragma unroll
        for (int j = 0; j < 4; ++j)
          kb[(size_t)(row0 + j) * 512 + col] = f2bf(acc[mt][nt][j]);
      } else {  // V^T path: 4 consecutive m -> one 8B store
        int bb = row0 >> 11, m = row0 & 2047;
        int hd = col - 512;  // h*64+d
        uint2 w;
        w.x = pkbf(acc[mt][nt][0], acc[mt][nt][1]);
        w.y = pkbf(acc[mt][nt][2], acc[mt][nt][3]);
        *(uint2*)(vtb + ((size_t)bb * 512 + hd) * 2048 + m) = w;
      }
    }
}

// out-projection with fused KV-split combine + rls LDS prologue (r23, ~14.5us).
__global__ __launch_bounds__(256) void outproj_kernel(
    const unsigned short* __restrict__ poA, const unsigned short* __restrict__ poB,
    const float* __restrict__ ls, const unsigned short* __restrict__ Bt,
    float* __restrict__ C0, const float* __restrict__ bias) {
  __shared__ unsigned short As[64][72];
  __shared__ unsigned short Bs[128][72];
  __shared__ float rls[512];  // [h][row-bm]
  const int bm = blockIdx.y * 64, bn = blockIdx.x * 128;
  const int K = 512, N = 512;
  const int tid = threadIdx.x;
  const int wave = tid >> 6, lane = tid & 63;
  const int wr = (wave >> 1) * 32, wc = (wave & 1) * 64;
  const int l15 = lane & 15, lq = lane >> 4;
  const int sr = tid >> 3, sc = (tid & 7) * 8;
  f32x4 acc[2][4] = {};

#pragma unroll
  for (int it = 0; it < 2; ++it) {
    int idx = tid + it * 256;          // 0..511
    int hh = idx >> 6, row = bm + (idx & 63);
    rls[idx] = 1.0f / (ls[(size_t)hh * 8192 + row] + ls[65536 + (size_t)hh * 8192 + row]);
  }

  for (int k0 = 0; k0 < K; k0 += 64) {
    const int h = k0 >> 6;
    __syncthreads();
#pragma unroll
    for (int p = 0; p < 2; ++p) {
      int row = bm + sr + p * 32;
      uint4 ua = *(const uint4*)(poA + (size_t)row * 512 + k0 + sc);
      uint4 ub = *(const uint4*)(poB + (size_t)row * 512 + k0 + sc);
      float rl = rls[h * 64 + sr + p * 32];
      uint4 u;
      u.x = pkbf((bf2f_lo(ua.x) + bf2f_lo(ub.x)) * rl, (bf2f_hi(ua.x) + bf2f_hi(ub.x)) * rl);
      u.y = pkbf((bf2f_lo(ua.y) + bf2f_lo(ub.y)) * rl, (bf2f_hi(ua.y) + bf2f_hi(ub.y)) * rl);
      u.z = pkbf((bf2f_lo(ua.z) + bf2f_lo(ub.z)) * rl, (bf2f_hi(ua.z) + bf2f_hi(ub.z)) * rl);
      u.w = pkbf((bf2f_lo(ua.w) + bf2f_lo(ub.w)) * rl, (bf2f_hi(ua.w) + bf2f_hi(ub.w)) * rl);
      *(uint4*)(&As[sr + p * 32][sc]) = u;
    }
#pragma unroll
    for (int p = 0; p < 4; ++p)
      *(uint4*)(&Bs[sr + p * 32][sc]) = *(const uint4*)(Bt + (size_t)(bn + sr + p * 32) * K + k0 + sc);
    __syncthreads();
#pragma unroll
    for (int kk = 0; kk < 2; ++kk) {
      short8 af[2], bfr[4];
#pragma unroll
      for (int mt = 0; mt < 2; ++mt)
        af[mt] = *(const short8*)(&As[wr + mt * 16 + l15][kk * 32 + lq * 8]);
#pragma unroll
      for (int nt = 0; nt < 4; ++nt)
        bfr[nt] = *(const short8*)(&Bs[wc + nt * 16 + l15][kk * 32 + lq * 8]);
#pragma unroll
      for (int mt = 0; mt < 2; ++mt)
#pragma unroll
        for (int nt = 0; nt < 4; ++nt)
          acc[mt][nt] = __builtin_amdgcn_mfma_f32_16x16x32_bf16(af[mt], bfr[nt], acc[mt][nt], 0, 0, 0);
    }
  }

#pragma unroll
  for (int mt = 0; mt < 2; ++mt)
#pragma unroll
    for (int nt = 0; nt < 4; ++nt) {
      int row0 = bm + wr + mt * 16 + lq * 4;
      int col = bn + wc + nt * 16 + l15;
#pragma unroll
      for (int j = 0; j < 4; ++j)
        C0[(size_t)(row0 + j) * N + col] = acc[mt][nt][j] + bias[col];
    }
}

// Flash attention, KV-SPLIT, NO reg-prefetch: staging is direct global->LDS
// copies between BAR-A and BAR-B (compiler emits load+waitcnt+ds_write).
// This frees the 32 prefetch VGPRs -> demand ~127 fits launch_bounds(256,4)'s
// 128 budget -> 4 blocks/CU = 4 waves/SIMD (was 3; grid 1024, LDS 147KB/4).
// Exposed staging latency is covered by the added TLP (4 unsynced blocks/CU).
// Spill sentinel: WRITE must stay 16.9MB, VGPR_Count ~100-128.
__global__ __launch_bounds__(256, 4) void attn_kernel(
    const unsigned short* __restrict__ Q, const unsigned short* __restrict__ Kb,
    const unsigned short* __restrict__ Vt, const unsigned int* __restrict__ pmask,
    unsigned short* __restrict__ poA, unsigned short* __restrict__ poB,
    float* __restrict__ ls) {
  __shared__ unsigned short Ks[2][64][72];
  __shared__ unsigned short Vs[2][64][72];
  const int b = blockIdx.x >> 3, h = blockIdx.x & 7;
  const int z = blockIdx.z;
  const int tid = threadIdx.x, lane = tid & 63;
  const int wave = tid >> 6;
  const int l15 = lane & 15, lq = lane >> 4;
  const int wrow = blockIdx.y * 128 + wave * 32;

  const unsigned short* Qr0 = Q + (size_t)(b * 2048 + wrow + l15) * 512 + h * 64;
  const unsigned short* Qr1 = Q + (size_t)(b * 2048 + wrow + 16 + l15) * 512 + h * 64;
  short8 q00 = *(const short8*)(Qr0 + lq * 8);
  short8 q01 = *(const short8*)(Qr0 + 32 + lq * 8);
  short8 q10 = *(const short8*)(Qr1 + lq * 8);
  short8 q11 = *(const short8*)(Qr1 + 32 + lq * 8);

  const short8 vones = {0x3F80, 0x3F80, 0x3F80, 0x3F80,
                        0x3F80, 0x3F80, 0x3F80, 0x3F80};  // bf16 1.0 x8

  f32x4 o0[4] = {}, o1[4] = {};  // partial O^T per rt
  f32x4 ol0 = {}, ol1 = {};      // partial denominator via ones-MFMA

  const unsigned short* Kg = Kb + (size_t)b * 2048 * 512 + h * 64;
  const unsigned short* Vg = Vt + (size_t)(b * 8 + h) * 64 * 2048;
  const unsigned int* Pm = pmask + b * 1024;

  const int str = tid >> 3;        // 0..31
  const int stc = (tid & 7) * 8;   // elem col within 64
  // permuted K row (within 64-group): g -> (g&7>>1)*16 + ((g>>3)&3)*4 + (g&1);
  // perm(g+32) = perm(g) + 2
  const int kprow = ((str & 7) >> 1) * 16 + ((str >> 3) & 3) * 4 + (str & 1);

  const int mb0 = z << 10;  // this half's key range: [mb0, mb0+1024)

  for (int mb = mb0; mb < mb0 + 1024; mb += 128) {
    __syncthreads();  // BAR-A (WAR): all waves done reading the single buffer
    // direct global->LDS staging (no prefetch regs; TLP covers latency)
    *(uint4*)(&Ks[0][kprow][stc])     = *(const uint4*)(Kg + (size_t)(mb + str) * 512 + stc);
    *(uint4*)(&Ks[0][kprow + 2][stc]) = *(const uint4*)(Kg + (size_t)(mb + str + 32) * 512 + stc);
    *(uint4*)(&Ks[1][kprow][stc])     = *(const uint4*)(Kg + (size_t)(mb + 64 + str) * 512 + stc);
    *(uint4*)(&Ks[1][kprow + 2][stc]) = *(const uint4*)(Kg + (size_t)(mb + 64 + str + 32) * 512 + stc);
    *(uint4*)(&Vs[0][str][stc])       = *(const uint4*)(Vg + (size_t)str * 2048 + mb + stc);
    *(uint4*)(&Vs[0][str + 32][stc])  = *(const uint4*)(Vg + (size_t)(str + 32) * 2048 + mb + stc);
    *(uint4*)(&Vs[1][str][stc])       = *(const uint4*)(Vg + (size_t)str * 2048 + mb + 64 + stc);
    *(uint4*)(&Vs[1][str + 32][stc])  = *(const uint4*)(Vg + (size_t)(str + 32) * 2048 + mb + 64 + stc);
    __syncthreads();  // BAR-B (RAW): tile visible

#pragma unroll
    for (int g = 0; g < 2; ++g) {
      // mask patterns for this 64-key group (L2-hot, 16KB table)
      const uint4 m0 = *(const uint4*)(Pm + ((mb >> 6) + g) * 32 + lq * 8);
      const uint4 m1 = *(const uint4*)(Pm + ((mb >> 6) + g) * 32 + lq * 8 + 4);

      // swapped QK^T on permuted keys: kappa = (j>>1)*32 + lq*8 + 2ct + (j&1)
      f32x4 s0[4] = {}, s1[4] = {};
#pragma unroll
      for (int ct = 0; ct < 4; ++ct) {
        short8 kf = *(const short8*)(&Ks[g][ct * 16 + l15][lq * 8]);
        s0[ct] = __builtin_amdgcn_mfma_f32_16x16x32_bf16(kf, q00, s0[ct], 0, 0, 0);
        s1[ct] = __builtin_amdgcn_mfma_f32_16x16x32_bf16(kf, q10, s1[ct], 0, 0, 0);
      }
#pragma unroll
      for (int ct = 0; ct < 4; ++ct) {
        short8 kf = *(const short8*)(&Ks[g][ct * 16 + l15][32 + lq * 8]);
        s0[ct] = __builtin_amdgcn_mfma_f32_16x16x32_bf16(kf, q01, s0[ct], 0, 0, 0);
        s1[ct] = __builtin_amdgcn_mfma_f32_16x16x32_bf16(kf, q11, s1[ct], 0, 0, 0);
      }

      // P = exp2(s) (m=0, shift-invariant), packed to bf16 pairs
      unsigned int xp0[4][2], xp1[4][2];
#pragma unroll
      for (int ct = 0; ct < 4; ++ct) {
        float a0 = __builtin_amdgcn_exp2f(s0[ct][0]);
        float a1 = __builtin_amdgcn_exp2f(s0[ct][1]);
        float a2 = __builtin_amdgcn_exp2f(s0[ct][2]);
        float a3 = __builtin_amdgcn_exp2f(s0[ct][3]);
        xp0[ct][0] = pkbf(a0, a1);
        xp0[ct][1] = pkbf(a2, a3);
        float c0 = __builtin_amdgcn_exp2f(s1[ct][0]);
        float c1 = __builtin_amdgcn_exp2f(s1[ct][1]);
        float c2 = __builtin_amdgcn_exp2f(s1[ct][2]);
        float c3 = __builtin_amdgcn_exp2f(s1[ct][3]);
        xp1[ct][0] = pkbf(c0, c1);
        xp1[ct][1] = pkbf(c2, c3);
      }

      // mask: zero packed P of masked keys (patterns shared across rt)
      xp0[0][0] &= m0.x; xp0[0][1] &= m0.y; xp0[1][0] &= m0.z; xp0[1][1] &= m0.w;
      xp0[2][0] &= m1.x; xp0[2][1] &= m1.y; xp0[3][0] &= m1.z; xp0[3][1] &= m1.w;
      xp1[0][0] &= m0.x; xp1[0][1] &= m0.y; xp1[1][0] &= m0.z; xp1[1][1] &= m0.w;
      xp1[2][0] &= m1.x; xp1[2][1] &= m1.y; xp1[3][0] &= m1.z; xp1[3][1] &= m1.w;

      // PV swapped: O^T += V^T . P^T; denominator via ones-MFMA
#pragma unroll
      for (int kk = 0; kk < 2; ++kk) {
        union { unsigned int u[4]; short8 s8; } pc0, pc1;
        pc0.u[0] = xp0[0][kk]; pc0.u[1] = xp0[1][kk];
        pc0.u[2] = xp0[2][kk]; pc0.u[3] = xp0[3][kk];
        pc1.u[0] = xp1[0][kk]; pc1.u[1] = xp1[1][kk];
        pc1.u[2] = xp1[2][kk]; pc1.u[3] = xp1[3][kk];
#pragma unroll
        for (int dt = 0; dt < 4; ++dt) {
          short8 vf = *(const short8*)(&Vs[g][dt * 16 + l15][kk * 32 + lq * 8]);
          o0[dt] = __builtin_amdgcn_mfma_f32_16x16x32_bf16(vf, pc0.s8, o0[dt], 0, 0, 0);
          o1[dt] = __builtin_amdgcn_mfma_f32_16x16x32_bf16(vf, pc1.s8, o1[dt], 0, 0, 0);
        }
        ol0 = __builtin_amdgcn_mfma_f32_16x16x32_bf16(vones, pc0.s8, ol0, 0, 0, 0);
        ol1 = __builtin_amdgcn_mfma_f32_16x16x32_bf16(vones, pc1.s8, ol1, 0, 0, 0);
      }
    }
  }

  // write partial O (bf16, no normalization) + partial l (f32)
  unsigned short* po = z ? poB : poA;
  unsigned short* Or0 = po + (size_t)(b * 2048 + wrow + l15) * 512 + h * 64;
  unsigned short* Or1 = po + (size_t)(b * 2048 + wrow + 16 + l15) * 512 + h * 64;
#pragma unroll
  for (int dt = 0; dt < 4; ++dt) {
    *(unsigned int*)(Or0 + dt * 16 + lq * 4)     = pkbf(o0[dt][0], o0[dt][1]);
    *(unsigned int*)(Or0 + dt * 16 + lq * 4 + 2) = pkbf(o0[dt][2], o0[dt][3]);
    *(unsigned int*)(Or1 + dt * 16 + lq * 4)     = pkbf(o1[dt][0], o1[dt][1]);
    *(unsigned int*)(Or1 + dt * 16 + lq * 4 + 2) = pkbf(o1[dt][2], o1[dt][3]);
  }
  if (lq == 0) {  // one lane group per wave; all ol elements equal per q-col
    ls[((size_t)z * 8 + h) * 8192 + b * 2048 + wrow + l15]      = ol0[0];
    ls[((size_t)z * 8 + h) * 8192 + b * 2048 + wrow + 16 + l15] = ol1[0];
  }
}

extern "C" void kernel_launch(void* const* d_in, const int* in_sizes, int n_in,
                              void* d_out, int out_size, void* d_ws, size_t ws_size,
                              hipStream_t stream) {
  const float* x       = (const float*)d_in[0];
  const float* context = (const float*)d_in[1];
  const int*   mask    = (const int*)d_in[2];
  const float* Wq      = (const float*)d_in[3];
  const float* Wkv     = (const float*)d_in[4];
  const float* Wo      = (const float*)d_in[5];
  const float* bo      = (const float*)d_in[6];
  float* out = (float*)d_out;

  char* ws = (char*)d_ws;
  unsigned short* Wq_t  = (unsigned short*)(ws + 0);         //  512x512  bf16
  unsigned short* Wkv_t = (unsigned short*)(ws + 524288);    // 1024x512  bf16
  unsigned short* Wo_t  = (unsigned short*)(ws + 1572864);   //  512x512  bf16
  unsigned short* qb    = (unsigned short*)(ws + 2097152);   // 8192x512  bf16
  unsigned short* kb    = (unsigned short*)(ws + 10485760);  // 8192x512  bf16
  unsigned short* vtb   = (unsigned short*)(ws + 18874368);  // (b,h,d)x2048 bf16
  unsigned short* poA   = (unsigned short*)(ws + 27262976);  // 8192x512  bf16
  unsigned short* poB   = (unsigned short*)(ws + 35651584);  // 8192x512  bf16
  unsigned int* pmask   = (unsigned int*)(ws + 44040192);    // 4096 x u32
  float* ls             = (float*)(ws + 44056576);           // [2][8][8192] f32
  // total ws use: 44,580,864 bytes

  const float QSCALE = 0.125f * 1.44269504088896f;  // head_dim^-0.5 * log2(e)

  prep_kernel<<<dim3(16, 8, 4), 256, 0, stream>>>(Wq, Wkv, Wo, mask,
                                                  Wq_t, Wkv_t, Wo_t, pmask);
  proj_kernel<<<dim3(768), 256, 0, stream>>>(x, context, Wq_t, Wkv_t,
                                             qb, kb, vtb, QSCALE);
  attn_kernel<<<dim3(32, 16, 2), 256, 0, stream>>>(qb, kb, vtb, pmask,
                                                   poA, poB, ls);
  outproj_kernel<<<dim3(4, 128), 256, 0, stream>>>(poA, poB, ls, Wo_t, out, bo);
}

// Round 25
// 103.912 us; speedup vs baseline: 1.0654x; 1.0654x over previous
//
#include <hip/hip_runtime.h>
#include <hip/hip_bf16.h>
#include <cstddef>

typedef __attribute__((ext_vector_type(8))) short short8;
typedef __attribute__((ext_vector_type(4))) float f32x4;

__device__ inline unsigned short f2bf(float f) {
  unsigned int u = __float_as_uint(f);
  u += 0x7fffu + ((u >> 16) & 1u);
  return (unsigned short)(u >> 16);
}
__device__ inline unsigned int pkbf(float a, float b) {
  __hip_bfloat162 h = __float22bfloat162_rn(make_float2(a, b));
  union { __hip_bfloat162 h2; unsigned int u; } cv;
  cv.h2 = h;
  return cv.u;
}
__device__ inline float bf2f_lo(unsigned int u) {
  return __uint_as_float(u << 16);
}
__device__ inline float bf2f_hi(unsigned int u) {
  return __uint_as_float(u & 0xFFFF0000u);
}

// Fused prep: z=0/1/2 -> transpose+cast Wq/Wkv/Wo; z=3 -> mask AND-patterns.
__global__ __launch_bounds__(256) void prep_kernel(
    const float* __restrict__ Wq, const float* __restrict__ Wkv,
    const float* __restrict__ Wo, const int* __restrict__ mask,
    unsigned short* __restrict__ Wq_t, unsigned short* __restrict__ Wkv_t,
    unsigned short* __restrict__ Wo_t, unsigned int* __restrict__ pmask) {
  const int z = blockIdx.z;
  if (z == 3) {
    if (blockIdx.y != 0) return;
    int idx = blockIdx.x * 256 + threadIdx.x;  // 0..4095
    int bb = idx >> 10, rem = idx & 1023;
    int g = rem >> 5, rem2 = rem & 31;
    int lqv = rem2 >> 3, e = rem2 & 7;
    int ct = e >> 1, half = e & 1;
    // key kappa(ct,lq,j) = (j>>1)*32 + lq*8 + 2ct + (j&1); u32 packs j=2h,2h+1
    int key0 = g * 64 + half * 32 + lqv * 8 + 2 * ct;
    const int* mb = mask + bb * 2048;
    pmask[idx] = (mb[key0] ? 0xFFFFu : 0u) | (mb[key0 + 1] ? 0xFFFF0000u : 0u);
    return;
  }
  const float* src = (z == 0) ? Wq : (z == 1) ? Wkv : Wo;
  unsigned short* dst = (z == 0) ? Wq_t : (z == 1) ? Wkv_t : Wo_t;
  const int R = 512, C = (z == 1) ? 1024 : 512;
  if (blockIdx.x * 64 >= C) return;  // block-uniform
  __shared__ float tile[64][65];
  int c0 = blockIdx.x * 64, r0 = blockIdx.y * 64;
  int tx = threadIdx.x & 63, ty = threadIdx.x >> 6;
  for (int i = ty; i < 64; i += 4)
    tile[i][tx] = src[(size_t)(r0 + i) * C + c0 + tx];
  __syncthreads();
  for (int i = ty; i < 64; i += 4)
    dst[(size_t)(c0 + i) * R + r0 + tx] = f2bf(tile[tx][i]);
}

// Fused q+kv projection, reg-prefetch pipeline (r23, measured ~24us):
// BAR-A(WAR) -> cvt+ds_write from regs -> BAR-B(RAW) -> issue next chunk's
// loads (named scalars) -> compute. launch_bounds(256,3): ~150 total regs
// (VGPR ~86 + 64 acc) <= 170 budget, 3 blocks/CU.
__global__ __launch_bounds__(256, 3) void proj_kernel(
    const float* __restrict__ x, const float* __restrict__ context,
    const unsigned short* __restrict__ Wq_t, const unsigned short* __restrict__ Wkv_t,
    unsigned short* __restrict__ qb, unsigned short* __restrict__ kb,
    unsigned short* __restrict__ vtb, float qscale) {
  __shared__ unsigned short As[128][72];
  __shared__ unsigned short Bs[128][72];
  const int bid = blockIdx.x;
  const bool isq = bid < 256;  // block-uniform
  const int lid = isq ? bid : bid - 256;
  const float* Af = isq ? x : context;
  const unsigned short* Bt = isq ? Wq_t : Wkv_t;
  const int bn = (isq ? (lid & 3) : (lid & 7)) * 128;
  const int bm = (isq ? (lid >> 2) : (lid >> 3)) * 128;
  const int K = 512;
  const int tid = threadIdx.x;
  const int wave = tid >> 6, lane = tid & 63;
  const int wr = (wave >> 1) * 64, wc = (wave & 1) * 64;
  const int l15 = lane & 15, lq = lane >> 4;
  const int sr = tid >> 3, sc = (tid & 7) * 8;
  f32x4 acc[4][4] = {};

  // prefetch K-chunk 0 (named scalars only)
  float4 fA0a = *(const float4*)(Af + (size_t)(bm + sr) * K + sc);
  float4 fA0b = *(const float4*)(Af + (size_t)(bm + sr) * K + sc + 4);
  float4 fA1a = *(const float4*)(Af + (size_t)(bm + sr + 32) * K + sc);
  float4 fA1b = *(const float4*)(Af + (size_t)(bm + sr + 32) * K + sc + 4);
  float4 fA2a = *(const float4*)(Af + (size_t)(bm + sr + 64) * K + sc);
  float4 fA2b = *(const float4*)(Af + (size_t)(bm + sr + 64) * K + sc + 4);
  float4 fA3a = *(const float4*)(Af + (size_t)(bm + sr + 96) * K + sc);
  float4 fA3b = *(const float4*)(Af + (size_t)(bm + sr + 96) * K + sc + 4);
  uint4 uB0 = *(const uint4*)(Bt + (size_t)(bn + sr) * K + sc);
  uint4 uB1 = *(const uint4*)(Bt + (size_t)(bn + sr + 32) * K + sc);
  uint4 uB2 = *(const uint4*)(Bt + (size_t)(bn + sr + 64) * K + sc);
  uint4 uB3 = *(const uint4*)(Bt + (size_t)(bn + sr + 96) * K + sc);

  for (int k0 = 0; k0 < K; k0 += 64) {
    __syncthreads();  // BAR-A (WAR)
    uint4 u;
    u.x = pkbf(fA0a.x, fA0a.y); u.y = pkbf(fA0a.z, fA0a.w);
    u.z = pkbf(fA0b.x, fA0b.y); u.w = pkbf(fA0b.z, fA0b.w);
    *(uint4*)(&As[sr][sc]) = u;
    u.x = pkbf(fA1a.x, fA1a.y); u.y = pkbf(fA1a.z, fA1a.w);
    u.z = pkbf(fA1b.x, fA1b.y); u.w = pkbf(fA1b.z, fA1b.w);
    *(uint4*)(&As[sr + 32][sc]) = u;
    u.x = pkbf(fA2a.x, fA2a.y); u.y = pkbf(fA2a.z, fA2a.w);
    u.z = pkbf(fA2b.x, fA2b.y); u.w = pkbf(fA2b.z, fA2b.w);
    *(uint4*)(&As[sr + 64][sc]) = u;
    u.x = pkbf(fA3a.x, fA3a.y); u.y = pkbf(fA3a.z, fA3a.w);
    u.z = pkbf(fA3b.x, fA3b.y); u.w = pkbf(fA3b.z, fA3b.w);
    *(uint4*)(&As[sr + 96][sc]) = u;
    *(uint4*)(&Bs[sr][sc])      = uB0;
    *(uint4*)(&Bs[sr + 32][sc]) = uB1;
    *(uint4*)(&Bs[sr + 64][sc]) = uB2;
    *(uint4*)(&Bs[sr + 96][sc]) = uB3;
    __syncthreads();  // BAR-B (RAW); prefetch never crosses a barrier
    if (k0 + 64 < K) {
      const int kn = k0 + 64;
      fA0a = *(const float4*)(Af + (size_t)(bm + sr) * K + kn + sc);
      fA0b = *(const float4*)(Af + (size_t)(bm + sr) * K + kn + sc + 4);
      fA1a = *(const float4*)(Af + (size_t)(bm + sr + 32) * K + kn + sc);
      fA1b = *(const float4*)(Af + (size_t)(bm + sr + 32) * K + kn + sc + 4);
      fA2a = *(const float4*)(Af + (size_t)(bm + sr + 64) * K + kn + sc);
      fA2b = *(const float4*)(Af + (size_t)(bm + sr + 64) * K + kn + sc + 4);
      fA3a = *(const float4*)(Af + (size_t)(bm + sr + 96) * K + kn + sc);
      fA3b = *(const float4*)(Af + (size_t)(bm + sr + 96) * K + kn + sc + 4);
      uB0 = *(const uint4*)(Bt + (size_t)(bn + sr) * K + kn + sc);
      uB1 = *(const uint4*)(Bt + (size_t)(bn + sr + 32) * K + kn + sc);
      uB2 = *(const uint4*)(Bt + (size_t)(bn + sr + 64) * K + kn + sc);
      uB3 = *(const uint4*)(Bt + (size_t)(bn + sr + 96) * K + kn + sc);
    }
#pragma unroll
    for (int kk = 0; kk < 2; ++kk) {
      short8 af[4], bfr[4];
#pragma unroll
      for (int mt = 0; mt < 4; ++mt)
        af[mt] = *(const short8*)(&As[wr + mt * 16 + l15][kk * 32 + lq * 8]);
#pragma unroll
      for (int nt = 0; nt < 4; ++nt)
        bfr[nt] = *(const short8*)(&Bs[wc + nt * 16 + l15][kk * 32 + lq * 8]);
#pragma unroll
      for (int mt = 0; mt < 4; ++mt)
#pragma unroll
        for (int nt = 0; nt < 4; ++nt)
          acc[mt][nt] = __builtin_amdgcn_mfma_f32_16x16x32_bf16(af[mt], bfr[nt], acc[mt][nt], 0, 0, 0);
    }
  }

#pragma unroll
  for (int mt = 0; mt < 4; ++mt)
#pragma unroll
    for (int nt = 0; nt < 4; ++nt) {
      int row0 = bm + wr + mt * 16 + lq * 4;
      int col = bn + wc + nt * 16 + l15;
      if (isq) {
#pragma unroll
        for (int j = 0; j < 4; ++j)
          qb[(size_t)(row0 + j) * 512 + col] = f2bf(acc[mt][nt][j] * qscale);
      } else if (col < 512) {
#pragma unroll
        for (int j = 0; j < 4; ++j)
          kb[(size_t)(row0 + j) * 512 + col] = f2bf(acc[mt][nt][j]);
      } else {  // V^T path: 4 consecutive m -> one 8B store
        int bb = row0 >> 11, m = row0 & 2047;
        int hd = col - 512;  // h*64+d
        uint2 w;
        w.x = pkbf(acc[mt][nt][0], acc[mt][nt][1]);
        w.y = pkbf(acc[mt][nt][2], acc[mt][nt][3]);
        *(uint2*)(vtb + ((size_t)bb * 512 + hd) * 2048 + m) = w;
      }
    }
}

// out-projection with fused KV-split combine + rls LDS prologue (r23, ~14.5us).
__global__ __launch_bounds__(256) void outproj_kernel(
    const unsigned short* __restrict__ poA, const unsigned short* __restrict__ poB,
    const float* __restrict__ ls, const unsigned short* __restrict__ Bt,
    float* __restrict__ C0, const float* __restrict__ bias) {
  __shared__ unsigned short As[64][72];
  __shared__ unsigned short Bs[128][72];
  __shared__ float rls[512];  // [h][row-bm]
  const int bm = blockIdx.y * 64, bn = blockIdx.x * 128;
  const int K = 512, N = 512;
  const int tid = threadIdx.x;
  const int wave = tid >> 6, lane = tid & 63;
  const int wr = (wave >> 1) * 32, wc = (wave & 1) * 64;
  const int l15 = lane & 15, lq = lane >> 4;
  const int sr = tid >> 3, sc = (tid & 7) * 8;
  f32x4 acc[2][4] = {};

#pragma unroll
  for (int it = 0; it < 2; ++it) {
    int idx = tid + it * 256;          // 0..511
    int hh = idx >> 6, row = bm + (idx & 63);
    rls[idx] = 1.0f / (ls[(size_t)hh * 8192 + row] + ls[65536 + (size_t)hh * 8192 + row]);
  }

  for (int k0 = 0; k0 < K; k0 += 64) {
    const int h = k0 >> 6;
    __syncthreads();
#pragma unroll
    for (int p = 0; p < 2; ++p) {
      int row = bm + sr + p * 32;
      uint4 ua = *(const uint4*)(poA + (size_t)row * 512 + k0 + sc);
      uint4 ub = *(const uint4*)(poB + (size_t)row * 512 + k0 + sc);
      float rl = rls[h * 64 + sr + p * 32];
      uint4 u;
      u.x = pkbf((bf2f_lo(ua.x) + bf2f_lo(ub.x)) * rl, (bf2f_hi(ua.x) + bf2f_hi(ub.x)) * rl);
      u.y = pkbf((bf2f_lo(ua.y) + bf2f_lo(ub.y)) * rl, (bf2f_hi(ua.y) + bf2f_hi(ub.y)) * rl);
      u.z = pkbf((bf2f_lo(ua.z) + bf2f_lo(ub.z)) * rl, (bf2f_hi(ua.z) + bf2f_hi(ub.z)) * rl);
      u.w = pkbf((bf2f_lo(ua.w) + bf2f_lo(ub.w)) * rl, (bf2f_hi(ua.w) + bf2f_hi(ub.w)) * rl);
      *(uint4*)(&As[sr + p * 32][sc]) = u;
    }
#pragma unroll
    for (int p = 0; p < 4; ++p)
      *(uint4*)(&Bs[sr + p * 32][sc]) = *(const uint4*)(Bt + (size_t)(bn + sr + p * 32) * K + k0 + sc);
    __syncthreads();
#pragma unroll
    for (int kk = 0; kk < 2; ++kk) {
      short8 af[2], bfr[4];
#pragma unroll
      for (int mt = 0; mt < 2; ++mt)
        af[mt] = *(const short8*)(&As[wr + mt * 16 + l15][kk * 32 + lq * 8]);
#pragma unroll
      for (int nt = 0; nt < 4; ++nt)
        bfr[nt] = *(const short8*)(&Bs[wc + nt * 16 + l15][kk * 32 + lq * 8]);
#pragma unroll
      for (int mt = 0; mt < 2; ++mt)
#pragma unroll
        for (int nt = 0; nt < 4; ++nt)
          acc[mt][nt] = __builtin_amdgcn_mfma_f32_16x16x32_bf16(af[mt], bfr[nt], acc[mt][nt], 0, 0, 0);
    }
  }

#pragma unroll
  for (int mt = 0; mt < 2; ++mt)
#pragma unroll
    for (int nt = 0; nt < 4; ++nt) {
      int row0 = bm + wr + mt * 16 + lq * 4;
      int col = bn + wc + nt * 16 + l15;
#pragma unroll
      for (int j = 0; j < 4; ++j)
        C0[(size_t)(row0 + j) * N + col] = acc[mt][nt][j] + bias[col];
    }
}

// Flash attention, KV-SPLIT (blockIdx.z = half, 1024 keys each), r22/r23
// config: reg-prefetch + launch_bounds(256,3) (register demand ~160 incl
// AGPRs; the (256,4) 128 cap spills -- r21/r24). 3 waves/SIMD is this
// structure's occupancy ceiling. m=0 softmax partials are exact sums;
// combine fused into outproj. [Measured: 51us, WRITE 16.9MB clean]
__global__ __launch_bounds__(256, 3) void attn_kernel(
    const unsigned short* __restrict__ Q, const unsigned short* __restrict__ Kb,
    const unsigned short* __restrict__ Vt, const unsigned int* __restrict__ pmask,
    unsigned short* __restrict__ poA, unsigned short* __restrict__ poB,
    float* __restrict__ ls) {
  __shared__ unsigned short Ks[2][64][72];
  __shared__ unsigned short Vs[2][64][72];
  const int b = blockIdx.x >> 3, h = blockIdx.x & 7;
  const int z = blockIdx.z;
  const int tid = threadIdx.x, lane = tid & 63;
  const int wave = tid >> 6;
  const int l15 = lane & 15, lq = lane >> 4;
  const int wrow = blockIdx.y * 128 + wave * 32;

  const unsigned short* Qr0 = Q + (size_t)(b * 2048 + wrow + l15) * 512 + h * 64;
  const unsigned short* Qr1 = Q + (size_t)(b * 2048 + wrow + 16 + l15) * 512 + h * 64;
  short8 q00 = *(const short8*)(Qr0 + lq * 8);
  short8 q01 = *(const short8*)(Qr0 + 32 + lq * 8);
  short8 q10 = *(const short8*)(Qr1 + lq * 8);
  short8 q11 = *(const short8*)(Qr1 + 32 + lq * 8);

  const short8 vones = {0x3F80, 0x3F80, 0x3F80, 0x3F80,
                        0x3F80, 0x3F80, 0x3F80, 0x3F80};  // bf16 1.0 x8

  f32x4 o0[4] = {}, o1[4] = {};  // partial O^T per rt
  f32x4 ol0 = {}, ol1 = {};      // partial denominator via ones-MFMA

  const unsigned short* Kg = Kb + (size_t)b * 2048 * 512 + h * 64;
  const unsigned short* Vg = Vt + (size_t)(b * 8 + h) * 64 * 2048;
  const unsigned int* Pm = pmask + b * 1024;

  const int str = tid >> 3;        // 0..31
  const int stc = (tid & 7) * 8;   // elem col within 64
  // permuted K row (within 64-group): g -> (g&7>>1)*16 + ((g>>3)&3)*4 + (g&1);
  // perm(g+32) = perm(g) + 2
  const int kprow = ((str & 7) >> 1) * 16 + ((str >> 3) & 3) * 4 + (str & 1);

  const int mb0 = z << 10;  // this half's key range: [mb0, mb0+1024)

  // prefetch first tile (named scalars only)
  uint4 krA0 = *(const uint4*)(Kg + (size_t)(mb0 + str) * 512 + stc);
  uint4 krA1 = *(const uint4*)(Kg + (size_t)(mb0 + str + 32) * 512 + stc);
  uint4 krB0 = *(const uint4*)(Kg + (size_t)(mb0 + 64 + str) * 512 + stc);
  uint4 krB1 = *(const uint4*)(Kg + (size_t)(mb0 + 64 + str + 32) * 512 + stc);
  uint4 vrA0 = *(const uint4*)(Vg + (size_t)str * 2048 + mb0 + stc);
  uint4 vrA1 = *(const uint4*)(Vg + (size_t)(str + 32) * 2048 + mb0 + stc);
  uint4 vrB0 = *(const uint4*)(Vg + (size_t)str * 2048 + mb0 + 64 + stc);
  uint4 vrB1 = *(const uint4*)(Vg + (size_t)(str + 32) * 2048 + mb0 + 64 + stc);

  for (int mb = mb0; mb < mb0 + 1024; mb += 128) {
    __syncthreads();  // BAR-A (WAR): all waves done reading the single buffer
    // implicit vmcnt wait on staged regs here (thread-local)
    *(uint4*)(&Ks[0][kprow][stc])     = krA0;
    *(uint4*)(&Ks[0][kprow + 2][stc]) = krA1;
    *(uint4*)(&Ks[1][kprow][stc])     = krB0;
    *(uint4*)(&Ks[1][kprow + 2][stc]) = krB1;
    *(uint4*)(&Vs[0][str][stc])       = vrA0;
    *(uint4*)(&Vs[0][str + 32][stc])  = vrA1;
    *(uint4*)(&Vs[1][str][stc])       = vrB0;
    *(uint4*)(&Vs[1][str + 32][stc])  = vrB1;
    __syncthreads();  // BAR-B (RAW): tile visible
    if (mb + 128 < mb0 + 1024) {  // prefetch next tile; lands during compute
      const int nx = mb + 128;
      krA0 = *(const uint4*)(Kg + (size_t)(nx + str) * 512 + stc);
      krA1 = *(const uint4*)(Kg + (size_t)(nx + str + 32) * 512 + stc);
      krB0 = *(const uint4*)(Kg + (size_t)(nx + 64 + str) * 512 + stc);
      krB1 = *(const uint4*)(Kg + (size_t)(nx + 64 + str + 32) * 512 + stc);
      vrA0 = *(const uint4*)(Vg + (size_t)str * 2048 + nx + stc);
      vrA1 = *(const uint4*)(Vg + (size_t)(str + 32) * 2048 + nx + stc);
      vrB0 = *(const uint4*)(Vg + (size_t)str * 2048 + nx + 64 + stc);
      vrB1 = *(const uint4*)(Vg + (size_t)(str + 32) * 2048 + nx + 64 + stc);
    }

#pragma unroll
    for (int g = 0; g < 2; ++g) {
      // mask patterns for this 64-key group (L2-hot, 16KB table)
      const uint4 m0 = *(const uint4*)(Pm + ((mb >> 6) + g) * 32 + lq * 8);
      const uint4 m1 = *(const uint4*)(Pm + ((mb >> 6) + g) * 32 + lq * 8 + 4);

      // swapped QK^T on permuted keys: kappa = (j>>1)*32 + lq*8 + 2ct + (j&1)
      f32x4 s0[4] = {}, s1[4] = {};
#pragma unroll
      for (int ct = 0; ct < 4; ++ct) {
        short8 kf = *(const short8*)(&Ks[g][ct * 16 + l15][lq * 8]);
        s0[ct] = __builtin_amdgcn_mfma_f32_16x16x32_bf16(kf, q00, s0[ct], 0, 0, 0);
        s1[ct] = __builtin_amdgcn_mfma_f32_16x16x32_bf16(kf, q10, s1[ct], 0, 0, 0);
      }
#pragma unroll
      for (int ct = 0; ct < 4; ++ct) {
        short8 kf = *(const short8*)(&Ks[g][ct * 16 + l15][32 + lq * 8]);
        s0[ct] = __builtin_amdgcn_mfma_f32_16x16x32_bf16(kf, q01, s0[ct], 0, 0, 0);
        s1[ct] = __builtin_amdgcn_mfma_f32_16x16x32_bf16(kf, q11, s1[ct], 0, 0, 0);
      }

      // P = exp2(s) (m=0, shift-invariant), packed to bf16 pairs
      unsigned int xp0[4][2], xp1[4][2];
#pragma unroll
      for (int ct = 0; ct < 4; ++ct) {
        float a0 = __builtin_amdgcn_exp2f(s0[ct][0]);
        float a1 = __builtin_amdgcn_exp2f(s0[ct][1]);
        float a2 = __builtin_amdgcn_exp2f(s0[ct][2]);
        float a3 = __builtin_amdgcn_exp2f(s0[ct][3]);
        xp0[ct][0] = pkbf(a0, a1);
        xp0[ct][1] = pkbf(a2, a3);
        float c0 = __builtin_amdgcn_exp2f(s1[ct][0]);
        float c1 = __builtin_amdgcn_exp2f(s1[ct][1]);
        float c2 = __builtin_amdgcn_exp2f(s1[ct][2]);
        float c3 = __builtin_amdgcn_exp2f(s1[ct][3]);
        xp1[ct][0] = pkbf(c0, c1);
        xp1[ct][1] = pkbf(c2, c3);
      }

      // mask: zero packed P of masked keys (patterns shared across rt)
      xp0[0][0] &= m0.x; xp0[0][1] &= m0.y; xp0[1][0] &= m0.z; xp0[1][1] &= m0.w;
      xp0[2][0] &= m1.x; xp0[2][1] &= m1.y; xp0[3][0] &= m1.z; xp0[3][1] &= m1.w;
      xp1[0][0] &= m0.x; xp1[0][1] &= m0.y; xp1[1][0] &= m0.z; xp1[1][1] &= m0.w;
      xp1[2][0] &= m1.x; xp1[2][1] &= m1.y; xp1[3][0] &= m1.z; xp1[3][1] &= m1.w;

      // PV swapped: O^T += V^T . P^T; denominator via ones-MFMA
#pragma unroll
      for (int kk = 0; kk < 2; ++kk) {
        union { unsigned int u[4]; short8 s8; } pc0, pc1;
        pc0.u[0] = xp0[0][kk]; pc0.u[1] = xp0[1][kk];
        pc0.u[2] = xp0[2][kk]; pc0.u[3] = xp0[3][kk];
        pc1.u[0] = xp1[0][kk]; pc1.u[1] = xp1[1][kk];
        pc1.u[2] = xp1[2][kk]; pc1.u[3] = xp1[3][kk];
#pragma unroll
        for (int dt = 0; dt < 4; ++dt) {
          short8 vf = *(const short8*)(&Vs[g][dt * 16 + l15][kk * 32 + lq * 8]);
          o0[dt] = __builtin_amdgcn_mfma_f32_16x16x32_bf16(vf, pc0.s8, o0[dt], 0, 0, 0);
          o1[dt] = __builtin_amdgcn_mfma_f32_16x16x32_bf16(vf, pc1.s8, o1[dt], 0, 0, 0);
        }
        ol0 = __builtin_amdgcn_mfma_f32_16x16x32_bf16(vones, pc0.s8, ol0, 0, 0, 0);
        ol1 = __builtin_amdgcn_mfma_f32_16x16x32_bf16(vones, pc1.s8, ol1, 0, 0, 0);
      }
    }
  }

  // write partial O (bf16, no normalization) + partial l (f32)
  unsigned short* po = z ? poB : poA;
  unsigned short* Or0 = po + (size_t)(b * 2048 + wrow + l15) * 512 + h * 64;
  unsigned short* Or1 = po + (size_t)(b * 2048 + wrow + 16 + l15) * 512 + h * 64;
#pragma unroll
  for (int dt = 0; dt < 4; ++dt) {
    *(unsigned int*)(Or0 + dt * 16 + lq * 4)     = pkbf(o0[dt][0], o0[dt][1]);
    *(unsigned int*)(Or0 + dt * 16 + lq * 4 + 2) = pkbf(o0[dt][2], o0[dt][3]);
    *(unsigned int*)(Or1 + dt * 16 + lq * 4)     = pkbf(o1[dt][0], o1[dt][1]);
    *(unsigned int*)(Or1 + dt * 16 + lq * 4 + 2) = pkbf(o1[dt][2], o1[dt][3]);
  }
  if (lq == 0) {  // one lane group per wave; all ol elements equal per q-col
    ls[((size_t)z * 8 + h) * 8192 + b * 2048 + wrow + l15]      = ol0[0];
    ls[((size_t)z * 8 + h) * 8192 + b * 2048 + wrow + 16 + l15] = ol1[0];
  }
}

extern "C" void kernel_launch(void* const* d_in, const int* in_sizes, int n_in,
                              void* d_out, int out_size, void* d_ws, size_t ws_size,
                              hipStream_t stream) {
  const float* x       = (const float*)d_in[0];
  const float* context = (const float*)d_in[1];
  const int*   mask    = (const int*)d_in[2];
  const float* Wq      = (const float*)d_in[3];
  const float* Wkv     = (const float*)d_in[4];
  const float* Wo      = (const float*)d_in[5];
  const float* bo      = (const float*)d_in[6];
  float* out = (float*)d_out;

  char* ws = (char*)d_ws;
  unsigned short* Wq_t  = (unsigned short*)(ws + 0);         //  512x512  bf16
  unsigned short* Wkv_t = (unsigned short*)(ws + 524288);    // 1024x512  bf16
  unsigned short* Wo_t  = (unsigned short*)(ws + 1572864);   //  512x512  bf16
  unsigned short* qb    = (unsigned short*)(ws + 2097152);   // 8192x512  bf16
  unsigned short* kb    = (unsigned short*)(ws + 10485760);  // 8192x512  bf16
  unsigned short* vtb   = (unsigned short*)(ws + 18874368);  // (b,h,d)x2048 bf16
  unsigned short* poA   = (unsigned short*)(ws + 27262976);  // 8192x512  bf16
  unsigned short* poB   = (unsigned short*)(ws + 35651584);  // 8192x512  bf16
  unsigned int* pmask   = (unsigned int*)(ws + 44040192);    // 4096 x u32
  float* ls             = (float*)(ws + 44056576);           // [2][8][8192] f32
  // total ws use: 44,580,864 bytes

  const float QSCALE = 0.125f * 1.44269504088896f;  // head_dim^-0.5 * log2(e)

  prep_kernel<<<dim3(16, 8, 4), 256, 0, stream>>>(Wq, Wkv, Wo, mask,
                                                  Wq_t, Wkv_t, Wo_t, pmask);
  proj_kernel<<<dim3(768), 256, 0, stream>>>(x, context, Wq_t, Wkv_t,
                                             qb, kb, vtb, QSCALE);
  attn_kernel<<<dim3(32, 16, 2), 256, 0, stream>>>(qb, kb, vtb, pmask,
                                                   poA, poB, ls);
  outproj_kernel<<<dim3(4, 128), 256, 0, stream>>>(poA, poB, ls, Wo_t, out, bo);
}